// Round 2
// baseline (582.885 us; speedup 1.0000x reference)
//
#include <hip/hip_runtime.h>
#include <cstdint>

typedef __attribute__((ext_vector_type(8))) short short8;
typedef __attribute__((ext_vector_type(4))) float f32x4;

__device__ __forceinline__ unsigned short f2bf(float f) {
    uint32_t u = __builtin_bit_cast(uint32_t, f);
    u += 0x7FFFu + ((u >> 16) & 1u);   // round-to-nearest-even
    return (unsigned short)(u >> 16);
}

// ---------------------------------------------------------------------------
// setup: one block, 1024 threads. fp32 throughout.
//   out[0..16383]        = Gii = G = V V^T/128 * e^s
//   out[67649536]        = obj
//   ws bytes [0,32768)   = Wt bf16 swizzled   (Wt[c][k] = W[k][c] = (G M1)[c][k])
//   ws bytes [32768,65536)= Qt bf16 swizzled  (Q = M1 G M1 - M1, symmetric)
//   ws floats[16384..]   = Y fp32 scratch (G M1)
// swizzle: byte = (c*256 + k*2) ^ ((c&7)<<4)
// ---------------------------------------------------------------------------
__global__ __launch_bounds__(1024) void setup_kernel(
    const float* __restrict__ Kii, const float* __restrict__ V,
    const float* __restrict__ gscale, const int* __restrict__ dofp,
    float* __restrict__ out, float* __restrict__ ws)
{
    __shared__ float sA[128][132];
    __shared__ float sB[128][132];
    __shared__ float sd[128], srd[128], sg[128];
    __shared__ float red[16], red2[4];

    const int tid = threadIdx.x;
    const float egs = expf(gscale[0]);
    const int bi = (tid >> 5) * 4, bj = (tid & 31) * 4;

    // P0: V -> sA
    for (int i = tid; i < 16384; i += 1024) sA[i >> 7][i & 127] = V[i];
    __syncthreads();

    // P1: H = V V^T /128 * egs -> sB
    {
        float acc[4][4] = {};
        for (int k = 0; k < 128; k += 4) {
            f32x4 a[4], b[4];
            #pragma unroll
            for (int m = 0; m < 4; ++m) a[m] = *(const f32x4*)&sA[bi + m][k];
            #pragma unroll
            for (int n = 0; n < 4; ++n) b[n] = *(const f32x4*)&sA[bj + n][k];
            #pragma unroll
            for (int m = 0; m < 4; ++m)
                #pragma unroll
                for (int n = 0; n < 4; ++n)
                    acc[m][n] += a[m][0]*b[n][0] + a[m][1]*b[n][1]
                               + a[m][2]*b[n][2] + a[m][3]*b[n][3];
        }
        const float sc = egs * (1.0f / 128.0f);
        #pragma unroll
        for (int m = 0; m < 4; ++m)
            #pragma unroll
            for (int n = 0; n < 4; ++n)
                sB[bi + m][bj + n] = acc[m][n] * sc;
    }
    __syncthreads();

    // P2: G -> out ; P3: K -> sA
    for (int i = tid; i < 16384; i += 1024) out[i] = sB[i >> 7][i & 127];
    for (int i = tid; i < 16384; i += 1024) sA[i >> 7][i & 127] = Kii[i];
    __syncthreads();

    // P4: dual LDL^T (delayed scaling, full trailing square kept symmetric)
    for (int k = 0; k < 127; ++k) {
        const float rdA = 1.0f / sA[k][k];
        const float rdB = 1.0f / sB[k][k];
        const int tot = (127 - k) << 7;
        for (int idx = tid; idx < tot; idx += 1024) {
            const int i = (idx >> 7) + k + 1, j = idx & 127;
            if (j > k) {
                sA[i][j] -= sA[i][k] * sA[j][k] * rdA;
                sB[i][j] -= sB[i][k] * sB[j][k] * rdB;
            }
        }
        __syncthreads();
    }
    if (tid < 128) {
        const float d = sA[tid][tid];
        sd[tid] = d; srd[tid] = 1.0f / d; sg[tid] = sB[tid][tid];
    }
    __syncthreads();

    // P5: X = Lunit^{-1} (unit lower) via Gauss-Jordan into sB
    for (int i = tid; i < 16384; i += 1024)
        sB[i >> 7][i & 127] = ((i >> 7) == (i & 127)) ? 1.0f : 0.0f;
    __syncthreads();
    for (int k = 0; k < 127; ++k) {
        const int tot = (127 - k) << 7;
        for (int idx = tid; idx < tot; idx += 1024) {
            const int i = (idx >> 7) + k + 1, j = idx & 127;
            if (j <= k) sB[i][j] -= (sA[i][k] * srd[k]) * sB[k][j];
        }
        __syncthreads();
    }

    // P6: M1 = X^T D^{-1} X -> sA   (K_ii inverse)
    {
        float acc[4][4] = {};
        for (int k = 0; k < 128; ++k) {
            f32x4 xa = *(const f32x4*)&sB[k][bi];
            f32x4 xb = *(const f32x4*)&sB[k][bj];
            const float r = srd[k];
            xa *= r;
            #pragma unroll
            for (int m = 0; m < 4; ++m)
                #pragma unroll
                for (int n = 0; n < 4; ++n)
                    acc[m][n] += xa[m] * xb[n];
        }
        #pragma unroll
        for (int m = 0; m < 4; ++m)
            #pragma unroll
            for (int n = 0; n < 4; ++n)
                sA[bi + m][bj + n] = acc[m][n];
    }
    __syncthreads();

    // P7: G -> sB; Y = G*M1 (= W^T) -> wsY fp32 + Wt bf16 swizzled; trace
    for (int i = tid; i < 16384; i += 1024) sB[i >> 7][i & 127] = out[i];
    __syncthreads();

    float tsum = 0.0f;
    for (int i = tid; i < 16384; i += 1024)
        tsum += sA[i >> 7][i & 127] * sB[i >> 7][i & 127];

    float* wsY = ws + 16384;
    {
        float acc[4][4] = {};
        for (int m0 = 0; m0 < 128; m0 += 4) {
            f32x4 ga[4], mb[4];
            #pragma unroll
            for (int r = 0; r < 4; ++r) ga[r] = *(const f32x4*)&sB[bi + r][m0];
            #pragma unroll
            for (int s = 0; s < 4; ++s) mb[s] = *(const f32x4*)&sA[m0 + s][bj];
            #pragma unroll
            for (int r = 0; r < 4; ++r)
                #pragma unroll
                for (int s = 0; s < 4; ++s)
                    #pragma unroll
                    for (int c = 0; c < 4; ++c)
                        acc[r][c] += ga[r][s] * mb[s][c];
        }
        #pragma unroll
        for (int r = 0; r < 4; ++r) {
            const int c = bi + r;
            #pragma unroll
            for (int n = 0; n < 4; ++n) wsY[c * 128 + bj + n] = acc[r][n];
            const uint32_t lo = (uint32_t)f2bf(acc[r][0]) | ((uint32_t)f2bf(acc[r][1]) << 16);
            const uint32_t hi = (uint32_t)f2bf(acc[r][2]) | ((uint32_t)f2bf(acc[r][3]) << 16);
            const uint32_t byteoff = (uint32_t)((c * 256 + bj * 2) ^ ((c & 7) << 4));
            *(uint2*)((char*)ws + byteoff) = make_uint2(lo, hi);
        }
    }
    __threadfence();
    __syncthreads();

    // P8: Q = M1*Y - M1 -> Qt bf16 swizzled (+32768 bytes)
    {
        float acc[4][4] = {};
        for (int m0 = 0; m0 < 128; m0 += 4) {
            f32x4 a[4], b[4];
            #pragma unroll
            for (int r = 0; r < 4; ++r) a[r] = *(const f32x4*)&sA[bi + r][m0];
            #pragma unroll
            for (int s = 0; s < 4; ++s) b[s] = *(const f32x4*)&wsY[(m0 + s) * 128 + bj];
            #pragma unroll
            for (int r = 0; r < 4; ++r)
                #pragma unroll
                for (int s = 0; s < 4; ++s)
                    #pragma unroll
                    for (int c = 0; c < 4; ++c)
                        acc[r][c] += a[r][s] * b[s][c];
        }
        #pragma unroll
        for (int r = 0; r < 4; ++r) {
            const int c = bi + r;
            float q[4];
            #pragma unroll
            for (int n = 0; n < 4; ++n) q[n] = acc[r][n] - sA[c][bj + n];
            const uint32_t lo = (uint32_t)f2bf(q[0]) | ((uint32_t)f2bf(q[1]) << 16);
            const uint32_t hi = (uint32_t)f2bf(q[2]) | ((uint32_t)f2bf(q[3]) << 16);
            const uint32_t byteoff = (uint32_t)((c * 256 + bj * 2) ^ ((c & 7) << 4));
            *(uint2*)((char*)ws + 32768 + byteoff) = make_uint2(lo, hi);
        }
    }

    // P9: reductions + obj
    const int wid = tid >> 6, lane = tid & 63;
    #pragma unroll
    for (int o = 32; o > 0; o >>= 1) tsum += __shfl_xor(tsum, o, 64);
    if (lane == 0) red[wid] = tsum;
    float lv = 0.0f;
    if (tid < 128) lv = logf(sd[tid]);
    else if (tid < 256) lv = logf(sg[tid - 128]);
    #pragma unroll
    for (int o = 32; o > 0; o >>= 1) lv += __shfl_xor(lv, o, 64);
    if (lane == 0 && wid < 4) red2[wid] = lv;
    __syncthreads();
    if (tid == 0) {
        float trace = 0.0f;
        #pragma unroll
        for (int i = 0; i < 16; ++i) trace += red[i];
        const float logdetK = red2[0] + red2[1];
        const float logdetG = red2[2] + red2[3];
        const float logdetKinv = -logdetK;
        const float dof = (float)dofp[0];
        out[67649536] = -0.5f * dof * (-(logdetG + logdetKinv) + trace - 128.0f);
    }
}

// ---------------------------------------------------------------------------
// main: Gti = T*W, gt = tt + rowsum((T*Q) o T). 128 rows/block, 4 waves.
// ---------------------------------------------------------------------------
__global__ __launch_bounds__(256, 2) void main_kernel(
    const float* __restrict__ Kti, const float* __restrict__ Kt,
    const float* __restrict__ ws, float* __restrict__ Gti,
    float* __restrict__ gt)
{
    __shared__ __align__(16) char smem[67584];  // Wt|Qt bf16 (64KB) then reused as sC f32[128][132]
    const int tid = threadIdx.x;
    const int lane = tid & 63, wid = tid >> 6;
    const int l15 = lane & 15, l4 = lane >> 4;
    const int brow = blockIdx.x * 128;

    {   // stage swizzled Wt|Qt image linearly (64 KB, L2-hot)
        f32x4* s4 = (f32x4*)smem;
        const f32x4* w4 = (const f32x4*)ws;
        for (int i = tid; i < 4096; i += 256) s4[i] = w4[i];
    }
    __syncthreads();

    const int wrow = wid * 32;
    f32x4 accW[2][8] = {};
    f32x4 accZ[2][8] = {};

    const float* tbase = Kti + (size_t)(brow + wrow + l15) * 128;

    for (int kc = 0; kc < 4; ++kc) {
        const int k0 = kc * 32 + l4 * 8;
        const float* p0 = tbase + k0;
        const float* p1 = p0 + 16 * 128;
        const f32x4 f0a = *(const f32x4*)p0;
        const f32x4 f0b = *(const f32x4*)(p0 + 4);
        const f32x4 f1a = *(const f32x4*)p1;
        const f32x4 f1b = *(const f32x4*)(p1 + 4);
        const short8 a0 = { (short)f2bf(f0a[0]), (short)f2bf(f0a[1]), (short)f2bf(f0a[2]), (short)f2bf(f0a[3]),
                            (short)f2bf(f0b[0]), (short)f2bf(f0b[1]), (short)f2bf(f0b[2]), (short)f2bf(f0b[3]) };
        const short8 a1 = { (short)f2bf(f1a[0]), (short)f2bf(f1a[1]), (short)f2bf(f1a[2]), (short)f2bf(f1a[3]),
                            (short)f2bf(f1b[0]), (short)f2bf(f1b[1]), (short)f2bf(f1b[2]), (short)f2bf(f1b[3]) };
        #pragma unroll
        for (int ct = 0; ct < 8; ++ct) {
            const int c = ct * 16 + l15;
            const int byteoff = (c * 256 + k0 * 2) ^ ((c & 7) << 4);
            const short8 bW = *(const short8*)(smem + byteoff);
            const short8 bQ = *(const short8*)(smem + 32768 + byteoff);
            accW[0][ct] = __builtin_amdgcn_mfma_f32_16x16x32_bf16(a0, bW, accW[0][ct], 0, 0, 0);
            accW[1][ct] = __builtin_amdgcn_mfma_f32_16x16x32_bf16(a1, bW, accW[1][ct], 0, 0, 0);
            accZ[0][ct] = __builtin_amdgcn_mfma_f32_16x16x32_bf16(a0, bQ, accZ[0][ct], 0, 0, 0);
            accZ[1][ct] = __builtin_amdgcn_mfma_f32_16x16x32_bf16(a1, bQ, accZ[1][ct], 0, 0, 0);
        }
    }

    // epilogue: gt = tt + sum_p Z[r][p] * T[r][p]   (C/D layout: col=l15, row=l4*4+reg)
    #pragma unroll
    for (int rt = 0; rt < 2; ++rt) {
        #pragma unroll
        for (int r = 0; r < 4; ++r) {
            const int row = brow + wrow + rt * 16 + l4 * 4 + r;
            const float* trow = Kti + (size_t)row * 128;
            float p = 0.0f;
            #pragma unroll
            for (int ct = 0; ct < 8; ++ct) p += accZ[rt][ct][r] * trow[ct * 16 + l15];
            p += __shfl_xor(p, 1, 64);
            p += __shfl_xor(p, 2, 64);
            p += __shfl_xor(p, 4, 64);
            p += __shfl_xor(p, 8, 64);
            if (l15 == 0) gt[row] = Kt[row] + p;
        }
    }

    __syncthreads();   // all LDS B-frag reads done -> reuse smem as sC
    {
        float* sC = (float*)smem;
        #pragma unroll
        for (int rt = 0; rt < 2; ++rt)
            #pragma unroll
            for (int ct = 0; ct < 8; ++ct)
                #pragma unroll
                for (int r = 0; r < 4; ++r)
                    sC[(wrow + rt * 16 + l4 * 4 + r) * 132 + ct * 16 + l15] = accW[rt][ct][r];
    }
    __syncthreads();
    {
        const float* sC = (const float*)smem;
        #pragma unroll
        for (int it = 0; it < 16; ++it) {
            const int lin = it * 256 + tid;
            const int row = lin >> 5, c4 = (lin & 31) * 4;
            const f32x4 v = *(const f32x4*)&sC[row * 132 + c4];
            *(f32x4*)(Gti + (size_t)(brow + row) * 128 + c4) = v;
        }
    }
}

extern "C" void kernel_launch(void* const* d_in, const int* in_sizes, int n_in,
                              void* d_out, int out_size, void* d_ws, size_t ws_size,
                              hipStream_t stream)
{
    const float* Kii = (const float*)d_in[0];
    const float* Kti = (const float*)d_in[1];
    const float* Kt  = (const float*)d_in[2];
    const float* V   = (const float*)d_in[3];
    const float* gs  = (const float*)d_in[4];
    const int*   dof = (const int*)d_in[5];
    float* out = (float*)d_out;
    float* ws  = (float*)d_ws;

    const int N = in_sizes[2];          // 524288
    const int nblocks = N / 128;        // 4096

    setup_kernel<<<1, 1024, 0, stream>>>(Kii, V, gs, dof, out, ws);
    main_kernel<<<nblocks, 256, 0, stream>>>(Kti, Kt, ws,
                                             out + 16384,          // Gti
                                             out + 67125248);      // gt
}

// Round 3
// 334.391 us; speedup vs baseline: 1.7431x; 1.7431x over previous
//
#include <hip/hip_runtime.h>
#include <cstdint>

typedef __attribute__((ext_vector_type(8))) short short8;
typedef __attribute__((ext_vector_type(4))) float f32x4;

__device__ __forceinline__ unsigned short f2bf(float f) {
    uint32_t u = __builtin_bit_cast(uint32_t, f);
    u += 0x7FFFu + ((u >> 16) & 1u);   // round-to-nearest-even
    return (unsigned short)(u >> 16);
}

// out float offsets: Gii 0, Gti 16384, gt 67125248, obj 67649536
// fp32 scratch lives INSIDE the Gti region (overwritten later by main):
#define SG_OFF   16384     // G fp32 [128][128]
#define SM1_OFF  32768     // M1 = Kii^-1
#define SY_OFF   49152     // Y = G*M1
#define SX_OFF   65536     // X = Lunit^-1 (unit lower, upper zeros)
#define SD_OFF   81920     // d[0..127], [128]=logdetK, [129]=logdetG, [132+bid]=trace partials
// ws bytes [0,32768) = Wt bf16 swizzled; [32768,65536) = Qt bf16 swizzled
// swizzle: byte = (c*256 + k*2) ^ ((c&7)<<4)

// ---------------------------------------------------------------------------
// k0: G = V V^T /128 * e^s  -> out[0..16K) (Gii) and scratch sG. 16 blocks.
// ---------------------------------------------------------------------------
__global__ __launch_bounds__(256) void k0_G(
    const float* __restrict__ V, const float* __restrict__ gs,
    float* __restrict__ out)
{
    float* sG = out + SG_OFF;
    const float egs = expf(gs[0]) * (1.0f / 128.0f);
    const int ty = threadIdx.x >> 5, tx = threadIdx.x & 31;
    const int r = blockIdx.x * 8 + ty;
    const f32x4* V4 = (const f32x4*)V;
    f32x4 acc = {0.f, 0.f, 0.f, 0.f};
    for (int kq = 0; kq < 32; ++kq) {
        const f32x4 vr = V4[r * 32 + kq];
        #pragma unroll
        for (int e = 0; e < 4; ++e) {
            const f32x4 vc = V4[(tx * 4 + e) * 32 + kq];
            acc[e] += vr[0]*vc[0] + vr[1]*vc[1] + vr[2]*vc[2] + vr[3]*vc[3];
        }
    }
    acc *= egs;
    *(f32x4*)&out[r * 128 + tx * 4] = acc;
    *(f32x4*)&sG[r * 128 + tx * 4] = acc;
}

// ---------------------------------------------------------------------------
// k1: register-resident fused dual-LDL^T (K and G) + Gauss-Jordan X = L^-1.
// 512 threads: thread (ty,tx) owns rows ty*8..+8, cols tx*4..+4 of rA,rB,rX.
// Only pivot col/row transits LDS (double-buffered, 1 barrier/step).
// ---------------------------------------------------------------------------
__global__ __launch_bounds__(512) void k1_factor(
    const float* __restrict__ Kii, float* __restrict__ out)
{
    __shared__ float colA[2][128], colB[2][128], rowX[2][128];
    __shared__ float sDk[128], sDg[128], sRed[4];

    const int tid = threadIdx.x;
    const int ty = tid >> 5, tx = tid & 31;
    const int I0 = ty * 8, J0 = tx * 4;
    const float* sG = out + SG_OFF;
    float* sX = out + SX_OFF;
    float* dbuf = out + SD_OFF;

    f32x4 rA[8], rB[8], rX[8];
    #pragma unroll
    for (int r = 0; r < 8; ++r) {
        rA[r] = *(const f32x4*)&Kii[(size_t)(I0 + r) * 128 + J0];
        rB[r] = *(const f32x4*)&sG[(I0 + r) * 128 + J0];
        f32x4 z = {0.f, 0.f, 0.f, 0.f};
        #pragma unroll
        for (int e = 0; e < 4; ++e) z[e] = (I0 + r == J0 + e) ? 1.0f : 0.0f;
        rX[r] = z;
    }
    // prologue: col 0 of A,B and row 0 of X into buffer 0
    if (tx == 0) {
        #pragma unroll
        for (int r = 0; r < 8; ++r) { colA[0][I0 + r] = rA[r][0]; colB[0][I0 + r] = rB[r][0]; }
    }
    if (ty == 0) {
        #pragma unroll
        for (int e = 0; e < 4; ++e) rowX[0][J0 + e] = rX[0][e];
    }
    __syncthreads();

    for (int k = 0; k < 127; ++k) {
        const int b = k & 1;
        const float dK = colA[b][k], dG = colB[b][k];
        const float rdK = 1.0f / dK, rdG = 1.0f / dG;
        if (tid == 0) { sDk[k] = dK; sDg[k] = dG; }

        f32x4 caj = *(const f32x4*)&colA[b][J0];
        f32x4 cbj = *(const f32x4*)&colB[b][J0];
        const f32x4 xj = *(const f32x4*)&rowX[b][J0];
        #pragma unroll
        for (int e = 0; e < 4; ++e)
            if (J0 + e <= k) { caj[e] = 0.0f; cbj[e] = 0.0f; }

        f32x4 ca0 = *(const f32x4*)&colA[b][I0];
        f32x4 ca1 = *(const f32x4*)&colA[b][I0 + 4];
        f32x4 cb0 = *(const f32x4*)&colB[b][I0];
        f32x4 cb1 = *(const f32x4*)&colB[b][I0 + 4];
        #pragma unroll
        for (int r = 0; r < 4; ++r) {
            if (I0 + r <= k)     { ca0[r] = 0.0f; cb0[r] = 0.0f; }
            if (I0 + 4 + r <= k) { ca1[r] = 0.0f; cb1[r] = 0.0f; }
        }

        if (I0 + 7 > k) {
            #pragma unroll
            for (int r = 0; r < 8; ++r) {
                const float am = (r < 4) ? ca0[r & 3] : ca1[r & 3];
                const float bm = (r < 4) ? cb0[r & 3] : cb1[r & 3];
                const float fA = am * rdK;
                const float fB = bm * rdG;
                rA[r] -= fA * caj;
                rB[r] -= fB * cbj;
                rX[r] -= fA * xj;
            }
        }

        // owners publish col/row k+1 into the other buffer
        const int kn = k + 1, bn = kn & 1;
        if (tx == (kn >> 2)) {
            const int es = kn & 3;
            #pragma unroll
            for (int ee = 0; ee < 4; ++ee) if (ee == es) {
                #pragma unroll
                for (int r = 0; r < 8; ++r) {
                    colA[bn][I0 + r] = rA[r][ee];
                    colB[bn][I0 + r] = rB[r][ee];
                }
            }
        }
        if (ty == (kn >> 3)) {
            const int rs = kn & 7;
            #pragma unroll
            for (int rr = 0; rr < 8; ++rr) if (rr == rs) {
                #pragma unroll
                for (int e = 0; e < 4; ++e) rowX[bn][J0 + e] = rX[rr][e];
            }
        }
        __syncthreads();
    }
    if (tid == 511) { sDk[127] = rA[7][3]; sDg[127] = rB[7][3]; }

    // dump X (upper entries are genuine zeros)
    #pragma unroll
    for (int r = 0; r < 8; ++r)
        *(f32x4*)&sX[(I0 + r) * 128 + J0] = rX[r];
    __syncthreads();

    // d, logdets
    if (tid < 128) {
        dbuf[tid] = sDk[tid];
        float lk = logf(sDk[tid]);
        float lg = logf(sDg[tid]);
        #pragma unroll
        for (int o = 32; o > 0; o >>= 1) { lk += __shfl_xor(lk, o, 64); lg += __shfl_xor(lg, o, 64); }
        if ((tid & 63) == 0) { sRed[(tid >> 6) * 2] = lk; sRed[(tid >> 6) * 2 + 1] = lg; }
    }
    __syncthreads();
    if (tid == 0) {
        dbuf[128] = sRed[0] + sRed[2];   // logdet K
        dbuf[129] = sRed[1] + sRed[3];   // logdet G
    }
}

// ---------------------------------------------------------------------------
// k2: M1 = X^T D^-1 X  (= Kii^-1). 16 blocks.
// ---------------------------------------------------------------------------
__global__ __launch_bounds__(256) void k2_M1(float* __restrict__ out)
{
    const float* sX = out + SX_OFF;
    const float* dbuf = out + SD_OFF;
    float* sM1 = out + SM1_OFF;
    __shared__ float srd[128];
    const int tid = threadIdx.x;
    if (tid < 128) srd[tid] = 1.0f / dbuf[tid];
    __syncthreads();
    const int ty = tid >> 5, tx = tid & 31;
    const int a = blockIdx.x * 8 + ty;
    const f32x4* X4 = (const f32x4*)sX;
    f32x4 acc = {0.f, 0.f, 0.f, 0.f};
    for (int k = a; k < 128; ++k) {          // X[k][a]=0 for k<a
        const float xa = sX[k * 128 + a] * srd[k];
        acc += xa * X4[k * 32 + tx];
    }
    *(f32x4*)&sM1[a * 128 + tx * 4] = acc;
}

// ---------------------------------------------------------------------------
// k3: Y = G*M1 -> scratch + Wt bf16 swizzled (Wt[c][k]=(G M1)[c][k]=W[k][c]);
//     trace partials per block. 16 blocks.
// ---------------------------------------------------------------------------
__global__ __launch_bounds__(256) void k3_Y(float* __restrict__ out, char* __restrict__ wsb)
{
    const float* sG = out + SG_OFF;
    const float* sM1 = out + SM1_OFF;
    float* sY = out + SY_OFF;
    float* dbuf = out + SD_OFF;
    const int tid = threadIdx.x;
    const int ty = tid >> 5, tx = tid & 31;
    const int c = blockIdx.x * 8 + ty;
    const f32x4* M14 = (const f32x4*)sM1;
    f32x4 acc = {0.f, 0.f, 0.f, 0.f};
    for (int m = 0; m < 128; ++m)
        acc += sG[c * 128 + m] * M14[m * 32 + tx];
    *(f32x4*)&sY[c * 128 + tx * 4] = acc;
    const uint32_t lo = (uint32_t)f2bf(acc[0]) | ((uint32_t)f2bf(acc[1]) << 16);
    const uint32_t hi = (uint32_t)f2bf(acc[2]) | ((uint32_t)f2bf(acc[3]) << 16);
    const uint32_t byteoff = (uint32_t)((c * 256 + tx * 8) ^ ((c & 7) << 4));
    *(uint2*)(wsb + byteoff) = make_uint2(lo, hi);
    // trace(Kii_inv * G^T) = sum(M1 .* G)
    float t;
    {
        const f32x4* G4 = (const f32x4*)sG;
        const int idx = blockIdx.x * 256 + tid;
        const f32x4 g = G4[idx], mm = M14[idx];
        t = g[0]*mm[0] + g[1]*mm[1] + g[2]*mm[2] + g[3]*mm[3];
    }
    #pragma unroll
    for (int o = 32; o > 0; o >>= 1) t += __shfl_xor(t, o, 64);
    __shared__ float sp[4];
    if ((tid & 63) == 0) sp[tid >> 6] = t;
    __syncthreads();
    if (tid == 0) dbuf[132 + blockIdx.x] = sp[0] + sp[1] + sp[2] + sp[3];
}

// ---------------------------------------------------------------------------
// k4: Q = M1*Y - M1 -> Qt bf16 swizzled (Q symmetric); finalize obj. 16 blocks.
// ---------------------------------------------------------------------------
__global__ __launch_bounds__(256) void k4_Q(
    float* __restrict__ out, char* __restrict__ wsb, const int* __restrict__ dofp)
{
    const float* sM1 = out + SM1_OFF;
    const float* sY = out + SY_OFF;
    const float* dbuf = out + SD_OFF;
    const int tid = threadIdx.x;
    const int ty = tid >> 5, tx = tid & 31;
    const int c = blockIdx.x * 8 + ty;
    const f32x4* Y4 = (const f32x4*)sY;
    const f32x4* M14 = (const f32x4*)sM1;
    f32x4 acc = -M14[c * 32 + tx];
    for (int m = 0; m < 128; ++m)
        acc += sM1[c * 128 + m] * Y4[m * 32 + tx];
    const uint32_t lo = (uint32_t)f2bf(acc[0]) | ((uint32_t)f2bf(acc[1]) << 16);
    const uint32_t hi = (uint32_t)f2bf(acc[2]) | ((uint32_t)f2bf(acc[3]) << 16);
    const uint32_t byteoff = (uint32_t)((c * 256 + tx * 8) ^ ((c & 7) << 4));
    *(uint2*)(wsb + 32768 + byteoff) = make_uint2(lo, hi);
    if (blockIdx.x == 0 && tid == 0) {
        float trace = 0.0f;
        for (int i = 0; i < 16; ++i) trace += dbuf[132 + i];
        const float ldK = dbuf[128], ldG = dbuf[129];
        const float dof = (float)dofp[0];
        out[67649536] = -0.5f * dof * (-(ldG - ldK) + trace - 128.0f);
    }
}

// ---------------------------------------------------------------------------
// main: Gti = T*W, gt = tt + rowsum((T*Q) o T). 128 rows/block, 4 waves.
// (unchanged from round 2)
// ---------------------------------------------------------------------------
__global__ __launch_bounds__(256, 2) void main_kernel(
    const float* __restrict__ Kti, const float* __restrict__ Kt,
    const float* __restrict__ ws, float* __restrict__ Gti,
    float* __restrict__ gt)
{
    __shared__ __align__(16) char smem[67584];
    const int tid = threadIdx.x;
    const int lane = tid & 63, wid = tid >> 6;
    const int l15 = lane & 15, l4 = lane >> 4;
    const int brow = blockIdx.x * 128;

    {
        f32x4* s4 = (f32x4*)smem;
        const f32x4* w4 = (const f32x4*)ws;
        for (int i = tid; i < 4096; i += 256) s4[i] = w4[i];
    }
    __syncthreads();

    const int wrow = wid * 32;
    f32x4 accW[2][8] = {};
    f32x4 accZ[2][8] = {};

    const float* tbase = Kti + (size_t)(brow + wrow + l15) * 128;

    for (int kc = 0; kc < 4; ++kc) {
        const int k0 = kc * 32 + l4 * 8;
        const float* p0 = tbase + k0;
        const float* p1 = p0 + 16 * 128;
        const f32x4 f0a = *(const f32x4*)p0;
        const f32x4 f0b = *(const f32x4*)(p0 + 4);
        const f32x4 f1a = *(const f32x4*)p1;
        const f32x4 f1b = *(const f32x4*)(p1 + 4);
        const short8 a0 = { (short)f2bf(f0a[0]), (short)f2bf(f0a[1]), (short)f2bf(f0a[2]), (short)f2bf(f0a[3]),
                            (short)f2bf(f0b[0]), (short)f2bf(f0b[1]), (short)f2bf(f0b[2]), (short)f2bf(f0b[3]) };
        const short8 a1 = { (short)f2bf(f1a[0]), (short)f2bf(f1a[1]), (short)f2bf(f1a[2]), (short)f2bf(f1a[3]),
                            (short)f2bf(f1b[0]), (short)f2bf(f1b[1]), (short)f2bf(f1b[2]), (short)f2bf(f1b[3]) };
        #pragma unroll
        for (int ct = 0; ct < 8; ++ct) {
            const int c = ct * 16 + l15;
            const int byteoff = (c * 256 + k0 * 2) ^ ((c & 7) << 4);
            const short8 bW = *(const short8*)(smem + byteoff);
            const short8 bQ = *(const short8*)(smem + 32768 + byteoff);
            accW[0][ct] = __builtin_amdgcn_mfma_f32_16x16x32_bf16(a0, bW, accW[0][ct], 0, 0, 0);
            accW[1][ct] = __builtin_amdgcn_mfma_f32_16x16x32_bf16(a1, bW, accW[1][ct], 0, 0, 0);
            accZ[0][ct] = __builtin_amdgcn_mfma_f32_16x16x32_bf16(a0, bQ, accZ[0][ct], 0, 0, 0);
            accZ[1][ct] = __builtin_amdgcn_mfma_f32_16x16x32_bf16(a1, bQ, accZ[1][ct], 0, 0, 0);
        }
    }

    #pragma unroll
    for (int rt = 0; rt < 2; ++rt) {
        #pragma unroll
        for (int r = 0; r < 4; ++r) {
            const int row = brow + wrow + rt * 16 + l4 * 4 + r;
            const float* trow = Kti + (size_t)row * 128;
            float p = 0.0f;
            #pragma unroll
            for (int ct = 0; ct < 8; ++ct) p += accZ[rt][ct][r] * trow[ct * 16 + l15];
            p += __shfl_xor(p, 1, 64);
            p += __shfl_xor(p, 2, 64);
            p += __shfl_xor(p, 4, 64);
            p += __shfl_xor(p, 8, 64);
            if (l15 == 0) gt[row] = Kt[row] + p;
        }
    }

    __syncthreads();
    {
        float* sC = (float*)smem;
        #pragma unroll
        for (int rt = 0; rt < 2; ++rt)
            #pragma unroll
            for (int ct = 0; ct < 8; ++ct)
                #pragma unroll
                for (int r = 0; r < 4; ++r)
                    sC[(wrow + rt * 16 + l4 * 4 + r) * 132 + ct * 16 + l15] = accW[rt][ct][r];
    }
    __syncthreads();
    {
        const float* sC = (const float*)smem;
        #pragma unroll
        for (int it = 0; it < 16; ++it) {
            const int lin = it * 256 + tid;
            const int row = lin >> 5, c4 = (lin & 31) * 4;
            const f32x4 v = *(const f32x4*)&sC[row * 132 + c4];
            *(f32x4*)(Gti + (size_t)(brow + row) * 128 + c4) = v;
        }
    }
}

extern "C" void kernel_launch(void* const* d_in, const int* in_sizes, int n_in,
                              void* d_out, int out_size, void* d_ws, size_t ws_size,
                              hipStream_t stream)
{
    const float* Kii = (const float*)d_in[0];
    const float* Kti = (const float*)d_in[1];
    const float* Kt  = (const float*)d_in[2];
    const float* V   = (const float*)d_in[3];
    const float* gs  = (const float*)d_in[4];
    const int*   dof = (const int*)d_in[5];
    float* out = (float*)d_out;
    float* ws  = (float*)d_ws;

    const int N = in_sizes[2];          // 524288
    const int nblocks = N / 128;        // 4096

    k0_G<<<16, 256, 0, stream>>>(V, gs, out);
    k1_factor<<<1, 512, 0, stream>>>(Kii, out);
    k2_M1<<<16, 256, 0, stream>>>(out);
    k3_Y<<<16, 256, 0, stream>>>(out, (char*)ws);
    k4_Q<<<16, 256, 0, stream>>>(out, (char*)ws, dof);
    main_kernel<<<nblocks, 256, 0, stream>>>(Kti, Kt, ws,
                                             out + 16384,          // Gti
                                             out + 67125248);      // gt
}

// Round 4
// 305.470 us; speedup vs baseline: 1.9082x; 1.0947x over previous
//
#include <hip/hip_runtime.h>
#include <cstdint>

typedef __attribute__((ext_vector_type(8))) short short8;
typedef __attribute__((ext_vector_type(4))) float f32x4;

__device__ __forceinline__ unsigned short f2bf(float f) {
    uint32_t u = __builtin_bit_cast(uint32_t, f);
    u += 0x7FFFu + ((u >> 16) & 1u);   // round-to-nearest-even
    return (unsigned short)(u >> 16);
}

// out float offsets: Gii 0, Gti 16384, gt 67125248, obj 67649536
// fp32 scratch lives INSIDE the Gti region (overwritten later by main):
#define SG_OFF   16384     // G fp32 [128][128]
#define SM1_OFF  32768     // M1 = Kii^-1
#define SY_OFF   49152     // Y = G*M1
#define SX_OFF   65536     // X = Lunit^-1 (unit lower, upper zeros)
#define SD_OFF   81920     // d[0..127], [128]=logdetK, [129]=logdetG, [132+bid]=trace partials
// ws bytes [0,32768) = Wt bf16 swizzled; [32768,65536) = Qt bf16 swizzled
// swizzle: byte = (c*256 + k*2) ^ ((c&7)<<4)

// ---------------------------------------------------------------------------
// k0: G = V V^T /128 * e^s  -> out[0..16K) (Gii) and scratch sG. 16 blocks.
// ---------------------------------------------------------------------------
__global__ __launch_bounds__(256) void k0_G(
    const float* __restrict__ V, const float* __restrict__ gs,
    float* __restrict__ out)
{
    float* sG = out + SG_OFF;
    const float egs = expf(gs[0]) * (1.0f / 128.0f);
    const int ty = threadIdx.x >> 5, tx = threadIdx.x & 31;
    const int r = blockIdx.x * 8 + ty;
    const f32x4* V4 = (const f32x4*)V;
    f32x4 acc = {0.f, 0.f, 0.f, 0.f};
    for (int kq = 0; kq < 32; ++kq) {
        const f32x4 vr = V4[r * 32 + kq];
        #pragma unroll
        for (int e = 0; e < 4; ++e) {
            const f32x4 vc = V4[(tx * 4 + e) * 32 + kq];
            acc[e] += vr[0]*vc[0] + vr[1]*vc[1] + vr[2]*vc[2] + vr[3]*vc[3];
        }
    }
    acc *= egs;
    *(f32x4*)&out[r * 128 + tx * 4] = acc;
    *(f32x4*)&sG[r * 128 + tx * 4] = acc;
}

// ---------------------------------------------------------------------------
// k1: register-resident fused dual-LDL^T (K and G) + Gauss-Jordan X = L^-1.
// (unchanged from round 3 — next round's target)
// ---------------------------------------------------------------------------
__global__ __launch_bounds__(512) void k1_factor(
    const float* __restrict__ Kii, float* __restrict__ out)
{
    __shared__ float colA[2][128], colB[2][128], rowX[2][128];
    __shared__ float sDk[128], sDg[128], sRed[4];

    const int tid = threadIdx.x;
    const int ty = tid >> 5, tx = tid & 31;
    const int I0 = ty * 8, J0 = tx * 4;
    const float* sG = out + SG_OFF;
    float* sX = out + SX_OFF;
    float* dbuf = out + SD_OFF;

    f32x4 rA[8], rB[8], rX[8];
    #pragma unroll
    for (int r = 0; r < 8; ++r) {
        rA[r] = *(const f32x4*)&Kii[(size_t)(I0 + r) * 128 + J0];
        rB[r] = *(const f32x4*)&sG[(I0 + r) * 128 + J0];
        f32x4 z = {0.f, 0.f, 0.f, 0.f};
        #pragma unroll
        for (int e = 0; e < 4; ++e) z[e] = (I0 + r == J0 + e) ? 1.0f : 0.0f;
        rX[r] = z;
    }
    if (tx == 0) {
        #pragma unroll
        for (int r = 0; r < 8; ++r) { colA[0][I0 + r] = rA[r][0]; colB[0][I0 + r] = rB[r][0]; }
    }
    if (ty == 0) {
        #pragma unroll
        for (int e = 0; e < 4; ++e) rowX[0][J0 + e] = rX[0][e];
    }
    __syncthreads();

    for (int k = 0; k < 127; ++k) {
        const int b = k & 1;
        const float dK = colA[b][k], dG = colB[b][k];
        const float rdK = 1.0f / dK, rdG = 1.0f / dG;
        if (tid == 0) { sDk[k] = dK; sDg[k] = dG; }

        f32x4 caj = *(const f32x4*)&colA[b][J0];
        f32x4 cbj = *(const f32x4*)&colB[b][J0];
        const f32x4 xj = *(const f32x4*)&rowX[b][J0];
        #pragma unroll
        for (int e = 0; e < 4; ++e)
            if (J0 + e <= k) { caj[e] = 0.0f; cbj[e] = 0.0f; }

        f32x4 ca0 = *(const f32x4*)&colA[b][I0];
        f32x4 ca1 = *(const f32x4*)&colA[b][I0 + 4];
        f32x4 cb0 = *(const f32x4*)&colB[b][I0];
        f32x4 cb1 = *(const f32x4*)&colB[b][I0 + 4];
        #pragma unroll
        for (int r = 0; r < 4; ++r) {
            if (I0 + r <= k)     { ca0[r] = 0.0f; cb0[r] = 0.0f; }
            if (I0 + 4 + r <= k) { ca1[r] = 0.0f; cb1[r] = 0.0f; }
        }

        if (I0 + 7 > k) {
            #pragma unroll
            for (int r = 0; r < 8; ++r) {
                const float am = (r < 4) ? ca0[r & 3] : ca1[r & 3];
                const float bm = (r < 4) ? cb0[r & 3] : cb1[r & 3];
                const float fA = am * rdK;
                const float fB = bm * rdG;
                rA[r] -= fA * caj;
                rB[r] -= fB * cbj;
                rX[r] -= fA * xj;
            }
        }

        const int kn = k + 1, bn = kn & 1;
        if (tx == (kn >> 2)) {
            const int es = kn & 3;
            #pragma unroll
            for (int ee = 0; ee < 4; ++ee) if (ee == es) {
                #pragma unroll
                for (int r = 0; r < 8; ++r) {
                    colA[bn][I0 + r] = rA[r][ee];
                    colB[bn][I0 + r] = rB[r][ee];
                }
            }
        }
        if (ty == (kn >> 3)) {
            const int rs = kn & 7;
            #pragma unroll
            for (int rr = 0; rr < 8; ++rr) if (rr == rs) {
                #pragma unroll
                for (int e = 0; e < 4; ++e) rowX[bn][J0 + e] = rX[rr][e];
            }
        }
        __syncthreads();
    }
    if (tid == 511) { sDk[127] = rA[7][3]; sDg[127] = rB[7][3]; }

    #pragma unroll
    for (int r = 0; r < 8; ++r)
        *(f32x4*)&sX[(I0 + r) * 128 + J0] = rX[r];
    __syncthreads();

    if (tid < 128) {
        dbuf[tid] = sDk[tid];
        float lk = logf(sDk[tid]);
        float lg = logf(sDg[tid]);
        #pragma unroll
        for (int o = 32; o > 0; o >>= 1) { lk += __shfl_xor(lk, o, 64); lg += __shfl_xor(lg, o, 64); }
        if ((tid & 63) == 0) { sRed[(tid >> 6) * 2] = lk; sRed[(tid >> 6) * 2 + 1] = lg; }
    }
    __syncthreads();
    if (tid == 0) {
        dbuf[128] = sRed[0] + sRed[2];   // logdet K
        dbuf[129] = sRed[1] + sRed[3];   // logdet G
    }
}

// ---------------------------------------------------------------------------
// k2: M1 = X^T D^-1 X  (= Kii^-1). 16 blocks.
// ---------------------------------------------------------------------------
__global__ __launch_bounds__(256) void k2_M1(float* __restrict__ out)
{
    const float* sX = out + SX_OFF;
    const float* dbuf = out + SD_OFF;
    float* sM1 = out + SM1_OFF;
    __shared__ float srd[128];
    const int tid = threadIdx.x;
    if (tid < 128) srd[tid] = 1.0f / dbuf[tid];
    __syncthreads();
    const int ty = tid >> 5, tx = tid & 31;
    const int a = blockIdx.x * 8 + ty;
    const f32x4* X4 = (const f32x4*)sX;
    f32x4 acc = {0.f, 0.f, 0.f, 0.f};
    for (int k = a; k < 128; ++k) {          // X[k][a]=0 for k<a
        const float xa = sX[k * 128 + a] * srd[k];
        acc += xa * X4[k * 32 + tx];
    }
    *(f32x4*)&sM1[a * 128 + tx * 4] = acc;
}

// ---------------------------------------------------------------------------
// k3: Y = G*M1 -> scratch + Wt bf16 swizzled; trace partials. 16 blocks.
// ---------------------------------------------------------------------------
__global__ __launch_bounds__(256) void k3_Y(float* __restrict__ out, char* __restrict__ wsb)
{
    const float* sG = out + SG_OFF;
    const float* sM1 = out + SM1_OFF;
    float* sY = out + SY_OFF;
    float* dbuf = out + SD_OFF;
    const int tid = threadIdx.x;
    const int ty = tid >> 5, tx = tid & 31;
    const int c = blockIdx.x * 8 + ty;
    const f32x4* M14 = (const f32x4*)sM1;
    f32x4 acc = {0.f, 0.f, 0.f, 0.f};
    for (int m = 0; m < 128; ++m)
        acc += sG[c * 128 + m] * M14[m * 32 + tx];
    *(f32x4*)&sY[c * 128 + tx * 4] = acc;
    const uint32_t lo = (uint32_t)f2bf(acc[0]) | ((uint32_t)f2bf(acc[1]) << 16);
    const uint32_t hi = (uint32_t)f2bf(acc[2]) | ((uint32_t)f2bf(acc[3]) << 16);
    const uint32_t byteoff = (uint32_t)((c * 256 + tx * 8) ^ ((c & 7) << 4));
    *(uint2*)(wsb + byteoff) = make_uint2(lo, hi);
    float t;
    {
        const f32x4* G4 = (const f32x4*)sG;
        const int idx = blockIdx.x * 256 + tid;
        const f32x4 g = G4[idx], mm = M14[idx];
        t = g[0]*mm[0] + g[1]*mm[1] + g[2]*mm[2] + g[3]*mm[3];
    }
    #pragma unroll
    for (int o = 32; o > 0; o >>= 1) t += __shfl_xor(t, o, 64);
    __shared__ float sp[4];
    if ((tid & 63) == 0) sp[tid >> 6] = t;
    __syncthreads();
    if (tid == 0) dbuf[132 + blockIdx.x] = sp[0] + sp[1] + sp[2] + sp[3];
}

// ---------------------------------------------------------------------------
// k4: Q = M1*Y - M1 -> Qt bf16 swizzled; finalize obj. 16 blocks.
// ---------------------------------------------------------------------------
__global__ __launch_bounds__(256) void k4_Q(
    float* __restrict__ out, char* __restrict__ wsb, const int* __restrict__ dofp)
{
    const float* sM1 = out + SM1_OFF;
    const float* sY = out + SY_OFF;
    const float* dbuf = out + SD_OFF;
    const int tid = threadIdx.x;
    const int ty = tid >> 5, tx = tid & 31;
    const int c = blockIdx.x * 8 + ty;
    const f32x4* Y4 = (const f32x4*)sY;
    const f32x4* M14 = (const f32x4*)sM1;
    f32x4 acc = -M14[c * 32 + tx];
    for (int m = 0; m < 128; ++m)
        acc += sM1[c * 128 + m] * Y4[m * 32 + tx];
    const uint32_t lo = (uint32_t)f2bf(acc[0]) | ((uint32_t)f2bf(acc[1]) << 16);
    const uint32_t hi = (uint32_t)f2bf(acc[2]) | ((uint32_t)f2bf(acc[3]) << 16);
    const uint32_t byteoff = (uint32_t)((c * 256 + tx * 8) ^ ((c & 7) << 4));
    *(uint2*)(wsb + 32768 + byteoff) = make_uint2(lo, hi);
    if (blockIdx.x == 0 && tid == 0) {
        float trace = 0.0f;
        for (int i = 0; i < 16; ++i) trace += dbuf[132 + i];
        const float ldK = dbuf[128], ldG = dbuf[129];
        const float dof = (float)dofp[0];
        out[67649536] = -0.5f * dof * (-(ldG - ldK) + trace - 128.0f);
    }
}

// ---------------------------------------------------------------------------
// main: Gti = T*W, gt = tt + rowsum((T*Q) o T).
// 256 rows/block, 512 threads (8 waves), 2048 blocks, 64KB LDS -> 2 blk/CU.
// All T-loads issued up front (one latency exposure); direct Gti stores.
// ---------------------------------------------------------------------------
__global__ __launch_bounds__(512) void main_kernel(
    const float* __restrict__ Kti, const float* __restrict__ Kt,
    const float* __restrict__ ws, float* __restrict__ Gti,
    float* __restrict__ gt)
{
    __shared__ __align__(16) char smem[65536];   // Wt|Qt bf16 swizzled image
    const int tid = threadIdx.x;
    const int lane = tid & 63, wid = tid >> 6;
    const int l15 = lane & 15, l4 = lane >> 4;
    const int brow = blockIdx.x * 256;
    const int wrow = wid * 32;

    const float* tbase = Kti + (size_t)(brow + wrow + l15) * 128;

    // 1) issue ALL 16 T-loads (256 B/lane in flight, one vmcnt drain)
    f32x4 t[4][4];
    #pragma unroll
    for (int kc = 0; kc < 4; ++kc) {
        const float* p0 = tbase + kc * 32 + l4 * 8;
        const float* p1 = p0 + 16 * 128;
        t[kc][0] = *(const f32x4*)p0;
        t[kc][1] = *(const f32x4*)(p0 + 4);
        t[kc][2] = *(const f32x4*)p1;
        t[kc][3] = *(const f32x4*)(p1 + 4);
    }

    // 2) stage ws -> LDS (L2/L3-hot), 128 B/thread
    {
        f32x4* s4 = (f32x4*)smem;
        const f32x4* w4 = (const f32x4*)ws;
        #pragma unroll
        for (int i = 0; i < 8; ++i) s4[tid + i * 512] = w4[tid + i * 512];
    }

    // 3) convert T to bf16 A-frags (waits the global loads)
    short8 a[4][2];
    #pragma unroll
    for (int kc = 0; kc < 4; ++kc) {
        a[kc][0] = { (short)f2bf(t[kc][0][0]), (short)f2bf(t[kc][0][1]), (short)f2bf(t[kc][0][2]), (short)f2bf(t[kc][0][3]),
                     (short)f2bf(t[kc][1][0]), (short)f2bf(t[kc][1][1]), (short)f2bf(t[kc][1][2]), (short)f2bf(t[kc][1][3]) };
        a[kc][1] = { (short)f2bf(t[kc][2][0]), (short)f2bf(t[kc][2][1]), (short)f2bf(t[kc][2][2]), (short)f2bf(t[kc][2][3]),
                     (short)f2bf(t[kc][3][0]), (short)f2bf(t[kc][3][1]), (short)f2bf(t[kc][3][2]), (short)f2bf(t[kc][3][3]) };
    }
    __syncthreads();

    // 4) uninterrupted 128-MFMA stream
    f32x4 accW[2][8] = {};
    f32x4 accZ[2][8] = {};
    #pragma unroll
    for (int kc = 0; kc < 4; ++kc) {
        const int k0 = kc * 32 + l4 * 8;
        #pragma unroll
        for (int ct = 0; ct < 8; ++ct) {
            const int c = ct * 16 + l15;
            const int byteoff = (c * 256 + k0 * 2) ^ ((c & 7) << 4);
            const short8 bW = *(const short8*)(smem + byteoff);
            const short8 bQ = *(const short8*)(smem + 32768 + byteoff);
            accW[0][ct] = __builtin_amdgcn_mfma_f32_16x16x32_bf16(a[kc][0], bW, accW[0][ct], 0, 0, 0);
            accW[1][ct] = __builtin_amdgcn_mfma_f32_16x16x32_bf16(a[kc][1], bW, accW[1][ct], 0, 0, 0);
            accZ[0][ct] = __builtin_amdgcn_mfma_f32_16x16x32_bf16(a[kc][0], bQ, accZ[0][ct], 0, 0, 0);
            accZ[1][ct] = __builtin_amdgcn_mfma_f32_16x16x32_bf16(a[kc][1], bQ, accZ[1][ct], 0, 0, 0);
        }
    }

    // 5) gt epilogue (C/D layout: col=l15, row=l4*4+reg); trow re-reads are L1/L2-hot
    #pragma unroll
    for (int rt = 0; rt < 2; ++rt) {
        #pragma unroll
        for (int r = 0; r < 4; ++r) {
            const int row = brow + wrow + rt * 16 + l4 * 4 + r;
            const float* trow = Kti + (size_t)row * 128;
            float p = 0.0f;
            #pragma unroll
            for (int ct = 0; ct < 8; ++ct) p += accZ[rt][ct][r] * trow[ct * 16 + l15];
            p += __shfl_xor(p, 1, 64);
            p += __shfl_xor(p, 2, 64);
            p += __shfl_xor(p, 4, 64);
            p += __shfl_xor(p, 8, 64);
            if (l15 == 0) gt[row] = Kt[row] + p;
        }
    }

    // 6) direct Gti stores from accW (16-lane / 64B coalesced granules)
    #pragma unroll
    for (int rt = 0; rt < 2; ++rt) {
        #pragma unroll
        for (int r = 0; r < 4; ++r) {
            float* grow = Gti + (size_t)(brow + wrow + rt * 16 + l4 * 4 + r) * 128 + l15;
            #pragma unroll
            for (int ct = 0; ct < 8; ++ct)
                grow[ct * 16] = accW[rt][ct][r];
        }
    }
}

extern "C" void kernel_launch(void* const* d_in, const int* in_sizes, int n_in,
                              void* d_out, int out_size, void* d_ws, size_t ws_size,
                              hipStream_t stream)
{
    const float* Kii = (const float*)d_in[0];
    const float* Kti = (const float*)d_in[1];
    const float* Kt  = (const float*)d_in[2];
    const float* V   = (const float*)d_in[3];
    const float* gs  = (const float*)d_in[4];
    const int*   dof = (const int*)d_in[5];
    float* out = (float*)d_out;
    float* ws  = (float*)d_ws;

    const int N = in_sizes[2];          // 524288
    const int nblocks = N / 256;        // 2048

    k0_G<<<16, 256, 0, stream>>>(V, gs, out);
    k1_factor<<<1, 512, 0, stream>>>(Kii, out);
    k2_M1<<<16, 256, 0, stream>>>(out);
    k3_Y<<<16, 256, 0, stream>>>(out, (char*)ws);
    k4_Q<<<16, 256, 0, stream>>>(out, (char*)ws, dof);
    main_kernel<<<nblocks, 512, 0, stream>>>(Kti, Kt, ws,
                                             out + 16384,          // Gti
                                             out + 67125248);      // gt
}